// Round 5
// baseline (631.572 us; speedup 1.0000x reference)
//
#include <hip/hip_runtime.h>
#include <math.h>

#define N_RAYS 2048
#define NSAMP  256
#define NPTS   (N_RAYS * NSAMP)
#define NCHUNK (NPTS / 64)
#define GRIDN  128
#define G2     (GRIDN * GRIDN)
#define G3     (GRIDN * GRIDN * GRIDN)
#define APPC   27
#define CHP    28            // padded channels in transposed volume
#define FEATC  128
#define K1PAD  160           // 150 padded to 160 (5 k-tiles of 32)
#define ASTR   168           // A_lds k-stride
#define HSTR   136           // h1_lds k-stride
#define H2STR  130           // h2 stride (aliases A_lds) — odd dword stride: conflict-free

typedef __attribute__((ext_vector_type(8))) short short8;
typedef __attribute__((ext_vector_type(4))) float float4v;

__device__ __forceinline__ unsigned short f2bf(float f) {
  unsigned int u = __float_as_uint(f);
  return (unsigned short)((u + 0x7FFFu + ((u >> 16) & 1u)) >> 16);
}
__device__ __forceinline__ float bf2f(unsigned short u) {
  return __uint_as_float(((unsigned int)u) << 16);
}

__device__ __forceinline__ void grid_coords(float cx, float cy, float cz,
                                            int& x0, int& y0, int& z0,
                                            float& fx, float& fy, float& fz) {
  float x = (cx + 1.0f) * 0.5f * 127.0f;
  float y = (cy + 1.0f) * 0.5f * 127.0f;
  float z = (cz + 1.0f) * 0.5f * 127.0f;
  float x0f = fminf(fmaxf(floorf(x), 0.0f), 126.0f);
  float y0f = fminf(fmaxf(floorf(y), 0.0f), 126.0f);
  float z0f = fminf(fmaxf(floorf(z), 0.0f), 126.0f);
  x0 = (int)x0f; y0 = (int)y0f; z0 = (int)z0f;
  fx = x - x0f; fy = y - y0f; fz = z - z0f;
}

// ---------------- density transpose: [z][y][x] -> [x][y][z] (32x32 LDS tiles per y)
__global__ __launch_bounds__(256)
void dvol_transpose(const float* __restrict__ dvol, float* __restrict__ dvolT) {
  __shared__ float tile[32][33];
  int y  = blockIdx.x & 127;
  int zt = ((blockIdx.x >> 7) & 3) * 32;
  int xt = (blockIdx.x >> 9) * 32;
  int tx = threadIdx.x & 31;
  int r0 = threadIdx.x >> 5;       // 0..7
  #pragma unroll
  for (int i = 0; i < 4; ++i) {
    int zr = r0 + i * 8;
    tile[zr][tx] = dvol[((zt + zr) * GRIDN + y) * GRIDN + xt + tx];
  }
  __syncthreads();
  #pragma unroll
  for (int i = 0; i < 4; ++i) {
    int xr = r0 + i * 8;
    dvolT[((xt + xr) * GRIDN + y) * GRIDN + zt + tx] = tile[tx][xr];
  }
}

// ---------------- ray kernel: alpha + wave-scan cumprod -> weights, acc, worklist, AABB
template <bool TRANS>
__global__ __launch_bounds__(256)
void ray_kernel(const float* __restrict__ rays_o, const float* __restrict__ rays_d,
                const float* __restrict__ dvol,     // layout [z][y][x] (TRANS=0) or [x][y][z] (TRANS=1)
                float* __restrict__ weights_ws, float* __restrict__ acc_ws,
                int* __restrict__ count, int* __restrict__ worklist,
                int* __restrict__ bounds) {   // [xmin,ymin,zmin,xmax,ymax,zmax]
  int r = blockIdx.x, s = threadIdx.x;
  int lane = s & 63, wv = s >> 6;
  float ox = rays_o[r*3+0], oy = rays_o[r*3+1], oz = rays_o[r*3+2];
  float dx = rays_d[r*3+0], dy = rays_d[r*3+1], dz = rays_d[r*3+2];
  float inv = rsqrtf(dx*dx + dy*dy + dz*dz);
  dx *= inv; dy *= inv; dz *= inv;
  float z = 2.0f + (4.0f / 255.0f) * (float)s;
  float px = ox + dx * z, py = oy + dy * z, pz = oz + dz * z;
  float cx = fminf(fmaxf((px + 1.5f) * (2.0f/3.0f) - 1.0f, -1.0f), 1.0f);
  float cy = fminf(fmaxf((py + 1.5f) * (2.0f/3.0f) - 1.0f, -1.0f), 1.0f);
  float cz = fminf(fmaxf((pz + 1.5f) * (2.0f/3.0f) - 1.0f, -1.0f), 1.0f);
  int x0, y0, z0; float fx, fy, fz;
  grid_coords(cx, cy, cz, x0, y0, z0, fx, fy, fz);
  float gx = 1.0f - fx, gy = 1.0f - fy, gz = 1.0f - fz;
  float sf;
  if (TRANS) {
    // [x][y][z]: z contiguous — wave's lanes read consecutive z runs
    int base = (x0 * GRIDN + y0) * GRIDN + z0;
    float v000 = dvol[base],            v001 = dvol[base + 1];
    float v010 = dvol[base + GRIDN],    v011 = dvol[base + GRIDN + 1];
    float v100 = dvol[base + G2],       v101 = dvol[base + G2 + 1];
    float v110 = dvol[base + G2+GRIDN], v111 = dvol[base + G2+GRIDN+1];
    float c00 = gz * v000 + fz * v001;
    float c01 = gz * v010 + fz * v011;
    float c10 = gz * v100 + fz * v101;
    float c11 = gz * v110 + fz * v111;
    sf = gx * (gy * c00 + fy * c01) + fx * (gy * c10 + fy * c11);
  } else {
    int base = (z0 * GRIDN + y0) * GRIDN + x0;
    sf = dvol[base]            * (gz*gy*gx) + dvol[base + 1]            * (gz*gy*fx)
       + dvol[base + GRIDN]    * (gz*fy*gx) + dvol[base + GRIDN + 1]    * (gz*fy*fx)
       + dvol[base + G2]       * (fz*gy*gx) + dvol[base + G2 + 1]       * (fz*gy*fx)
       + dvol[base + G2+GRIDN] * (fz*fy*gx) + dvol[base + G2+GRIDN+1]   * (fz*fy*fx);
  }
  float xv = sf - 10.0f;
  float sp = fmaxf(xv, 0.0f) + __logf(1.0f + __expf(-fabsf(xv)));
  float alpha = 1.0f - __expf(-sp * (100.0f / 255.0f));

  // wave-level inclusive prefix product of (1 - a + 1e-10)
  float tt = 1.0f - alpha + 1e-10f;
  float p = tt;
  #pragma unroll
  for (int d = 1; d < 64; d <<= 1) {
    float v = __shfl_up(p, d);
    if (lane >= d) p *= v;
  }
  __shared__ float wtot[4], wacc[4];
  if (lane == 63) wtot[wv] = p;
  __syncthreads();
  float pref = 1.0f;
  #pragma unroll
  for (int w2i = 0; w2i < 3; ++w2i) if (w2i < wv) pref *= wtot[w2i];
  float ex = __shfl_up(p, 1);
  if (lane == 0) ex = 1.0f;
  float T = pref * ex;
  float wgt = alpha * T;
  weights_ws[r * NSAMP + s] = wgt;

  // wave reduce: weight sum; AABB from endpoint lanes (coords monotone along ray)
  float sum = wgt;
  #pragma unroll
  for (int d = 32; d; d >>= 1) sum += __shfl_xor(sum, d);
  int xa = __shfl(x0, 0), xb = __shfl(x0, 63);
  int ya = __shfl(y0, 0), yb = __shfl(y0, 63);
  int za = __shfl(z0, 0), zb = __shfl(z0, 63);
  if (lane == 0) {
    wacc[wv] = sum;
    if (sum >= 1e-5f) {                    // live chunk -> enqueue + AABB
      int pos = atomicAdd(count, 1);
      worklist[pos] = r * 4 + wv;
      atomicMin(&bounds[0], min(xa, xb)); atomicMax(&bounds[3], max(xa, xb) + 1);
      atomicMin(&bounds[1], min(ya, yb)); atomicMax(&bounds[4], max(ya, yb) + 1);
      atomicMin(&bounds[2], min(za, zb)); atomicMax(&bounds[5], max(za, zb) + 1);
    }
  }
  __syncthreads();
  if (s == 0) acc_ws[r] = wacc[0] + wacc[1] + wacc[2] + wacc[3];
}

// ---------------- transpose app volume (AABB-restricted):
// [27][z][y][x] f32 -> [z][y][x][28] bf16, 2 voxels per thread
__global__ __launch_bounds__(256)
void transpose_kernel(const float* __restrict__ avol, unsigned short* __restrict__ appT,
                      const int* __restrict__ bounds) {
  int vblk = blockIdx.x * 512;            // block covers one z, 4 y-rows
  int zb = vblk >> 14;
  int yb = (vblk & 16383) >> 7;           // block covers y in [yb, yb+3]
  int zmin = bounds[2], zmax = bounds[5];
  int ymin = bounds[1], ymax = bounds[4];
  if (zb < zmin || zb > zmax) return;
  if (yb + 3 < ymin || yb > ymax) return;
  int v0 = vblk + threadIdx.x * 2;
  int y = (v0 & 16383) >> 7;
  int x = v0 & 127;
  if (y < ymin || y > ymax) return;
  int xmin = bounds[0], xmax = bounds[3];
  if (x + 1 < xmin || x > xmax) return;

  float2 v[APPC];
  #pragma unroll
  for (int c = 0; c < APPC; ++c) v[c] = *(const float2*)&avol[(size_t)c * G3 + v0];
  unsigned short* dst = appT + (size_t)v0 * CHP;
  #pragma unroll
  for (int i = 0; i < 7; ++i) {
    ushort4 o;
    o.x = f2bf(v[4*i+0].x); o.y = f2bf(v[4*i+1].x);
    o.z = (4*i+2 < APPC) ? f2bf(v[4*i+2].x) : (unsigned short)0;
    o.w = (4*i+3 < APPC) ? f2bf(v[4*i+3].x) : (unsigned short)0;
    *(ushort4*)&dst[4*i] = o;
  }
  #pragma unroll
  for (int i = 0; i < 7; ++i) {
    ushort4 o;
    o.x = f2bf(v[4*i+0].y); o.y = f2bf(v[4*i+1].y);
    o.z = (4*i+2 < APPC) ? f2bf(v[4*i+2].y) : (unsigned short)0;
    o.w = (4*i+3 < APPC) ? f2bf(v[4*i+3].y) : (unsigned short)0;
    *(ushort4*)&dst[CHP + 4*i] = o;
  }
}

// ---------------- weight prep
__global__ __launch_bounds__(256)
void prep_weights(const float* __restrict__ w1, const float* __restrict__ w2,
                  unsigned short* __restrict__ w1T, unsigned short* __restrict__ w2T) {
  int t = blockIdx.x * 256 + threadIdx.x;
  if (t < 128 * K1PAD) {
    int n = t / K1PAD, k = t - n * K1PAD;
    w1T[t] = (k < 150) ? f2bf(w1[k * 128 + n]) : (unsigned short)0;
  } else {
    int i = t - 128 * K1PAD;
    if (i < 128 * 128) {
      int n = i >> 7, k = i & 127;
      w2T[i] = f2bf(w2[k * 128 + n]);
    }
  }
}

// ---------------- persistent shade over compacted worklist
template <bool USET>
__global__ __launch_bounds__(256)
void shade_kernel(const float* __restrict__ rays_o, const float* __restrict__ rays_d,
                  const float* __restrict__ avol, const unsigned short* __restrict__ appT,
                  const unsigned short* __restrict__ w1T, const unsigned short* __restrict__ w2T,
                  const float* __restrict__ b1, const float* __restrict__ b2,
                  const float* __restrict__ w3, const float* __restrict__ b3,
                  const float* __restrict__ weights_ws, float* __restrict__ rgb_accum,
                  const int* __restrict__ count, int* __restrict__ work_ctr,
                  const int* __restrict__ worklist) {
  __shared__ unsigned short A_lds[64 * ASTR];   // reused as h2 (stride 130)
  __shared__ unsigned short h1_lds[64 * HSTR];
  __shared__ int s_idx, s_n;

  int t = threadIdx.x;
  int lane = t & 63, wv = t >> 6;

  if (t == 0) s_n = *count;

  for (;;) {
    __syncthreads();
    if (t == 0) s_idx = atomicAdd(work_ctr, 1);
    __syncthreads();
    if (s_idx >= s_n) break;
    int chunk = worklist[s_idx];
    int gp0 = chunk * 64;
    int r = gp0 >> 8;

    // ---- gather + positional encoding ----
    {
      int q = t & 3, pt = t >> 2;
      int gp = gp0 + pt, s = gp & 255;
      float ox = rays_o[r*3+0], oy = rays_o[r*3+1], oz = rays_o[r*3+2];
      float dx = rays_d[r*3+0], dy = rays_d[r*3+1], dz = rays_d[r*3+2];
      float inv = rsqrtf(dx*dx + dy*dy + dz*dz);
      dx *= inv; dy *= inv; dz *= inv;
      float z = 2.0f + (4.0f / 255.0f) * (float)s;
      float px = ox + dx * z, py = oy + dy * z, pz = oz + dz * z;
      float cx = fminf(fmaxf((px + 1.5f) * (2.0f/3.0f) - 1.0f, -1.0f), 1.0f);
      float cy = fminf(fmaxf((py + 1.5f) * (2.0f/3.0f) - 1.0f, -1.0f), 1.0f);
      float cz = fminf(fmaxf((pz + 1.5f) * (2.0f/3.0f) - 1.0f, -1.0f), 1.0f);
      int x0, y0, z0; float fxg, fyg, fzg;
      grid_coords(cx, cy, cz, x0, y0, z0, fxg, fyg, fzg);
      float gxg = 1.0f - fxg, gyg = 1.0f - fyg, gzg = 1.0f - fzg;
      float w8[8];
      w8[0] = gzg*gyg*gxg; w8[1] = gzg*gyg*fxg;
      w8[2] = gzg*fyg*gxg; w8[3] = gzg*fyg*fxg;
      w8[4] = fzg*gyg*gxg; w8[5] = fzg*gyg*fxg;
      w8[6] = fzg*fyg*gxg; w8[7] = fzg*fyg*fxg;
      int ibase = (z0 * GRIDN + y0) * GRIDN + x0;

      int vi = ibase + (q >> 1) * G2 + (q & 1) * GRIDN;
      float wA = w8[2*q], wB = w8[2*q+1];
      float part[27];
      if (USET) {
        const ushort4* c0 = (const ushort4*)(appT + (size_t)vi * CHP);
        const ushort4* c1 = (const ushort4*)(appT + (size_t)(vi + 1) * CHP);
        ushort4 a[7], b[7];
        #pragma unroll
        for (int i = 0; i < 7; ++i) { a[i] = c0[i]; b[i] = c1[i]; }
        #pragma unroll
        for (int c = 0; c < 27; ++c) {
          unsigned short ua = (&a[c >> 2].x)[c & 3];
          unsigned short ub = (&b[c >> 2].x)[c & 3];
          part[c] = wA * bf2f(ua) + wB * bf2f(ub);
        }
      } else {
        #pragma unroll
        for (int c = 0; c < 27; ++c) {
          const float* base = avol + (size_t)c * G3 + vi;
          part[c] = wA * base[0] + wB * base[1];
        }
      }
      #pragma unroll
      for (int c = 0; c < 27; ++c) {
        float v = part[c];
        v += __shfl_xor(v, 1);
        v += __shfl_xor(v, 2);
        part[c] = v;
      }
      float f[7];
      #pragma unroll
      for (int j = 0; j < 7; ++j) {
        float vlo = (q & 1) ? part[7 + j] : part[j];
        float vhi = (q & 1) ? part[(21 + j < 27) ? 21 + j : 26] : part[14 + j];
        f[j] = (q & 2) ? vhi : vlo;
      }
      unsigned short* Arow = A_lds + pt * ASTR;
      int cbase = 7 * q;
      #pragma unroll
      for (int j = 0; j < 7; ++j) {
        int c = cbase + j;
        if (c < 27) {
          float fv = f[j];
          Arow[c] = f2bf(fv);
          float s1 = __sinf(fv),      c1 = __cosf(fv);
          float s2 = __sinf(2.0f*fv), c2 = __cosf(2.0f*fv);
          Arow[30 + 2*c] = f2bf(s1); Arow[31 + 2*c] = f2bf(s2);
          Arow[84 + 2*c] = f2bf(c1); Arow[85 + 2*c] = f2bf(c2);
        }
      }
      if (q == 3) {
        float vd[3] = {dx, dy, dz};
        #pragma unroll
        for (int d = 0; d < 3; ++d) {
          Arow[27 + d] = f2bf(vd[d]);
          float s1 = __sinf(vd[d]),      c1 = __cosf(vd[d]);
          float s2 = __sinf(2.0f*vd[d]), c2 = __cosf(2.0f*vd[d]);
          Arow[138 + 2*d] = f2bf(s1); Arow[139 + 2*d] = f2bf(s2);
          Arow[144 + 2*d] = f2bf(c1); Arow[145 + 2*d] = f2bf(c2);
        }
      }
      if (q == 1) {
        #pragma unroll
        for (int i = 0; i < 5; ++i) *(unsigned int*)&Arow[150 + 2*i] = 0u;
      }
    }
    __syncthreads();

    // ---- MFMA MLP ----
    int nlo = lane & 15;
    int koff = (lane >> 4) * 8;
    int mrow = wv * 16 + nlo;

    short8 a1[5];
    #pragma unroll
    for (int kt = 0; kt < 5; ++kt)
      a1[kt] = *(const short8*)&A_lds[mrow * ASTR + kt * 32 + koff];
    #pragma unroll
    for (int nt = 0; nt < 8; ++nt) {
      float4v acc = {0.f, 0.f, 0.f, 0.f};
      #pragma unroll
      for (int kt = 0; kt < 5; ++kt) {
        short8 b = *(const short8*)&w1T[(nt * 16 + nlo) * K1PAD + kt * 32 + koff];
        acc = __builtin_amdgcn_mfma_f32_16x16x32_bf16(a1[kt], b, acc, 0, 0, 0);
      }
      float bv = b1[nt * 16 + nlo];
      #pragma unroll
      for (int rg = 0; rg < 4; ++rg) {
        int m = wv * 16 + (lane >> 4) * 4 + rg;
        float hv = fmaxf(acc[rg] + bv, 0.0f);
        h1_lds[m * HSTR + nt * 16 + nlo] = f2bf(hv);
      }
    }
    __syncthreads();

    short8 a2[4];
    #pragma unroll
    for (int kt = 0; kt < 4; ++kt)
      a2[kt] = *(const short8*)&h1_lds[mrow * HSTR + kt * 32 + koff];
    unsigned short* h2 = A_lds;
    #pragma unroll
    for (int nt = 0; nt < 8; ++nt) {
      float4v acc = {0.f, 0.f, 0.f, 0.f};
      #pragma unroll
      for (int kt = 0; kt < 4; ++kt) {
        short8 b = *(const short8*)&w2T[(nt * 16 + nlo) * FEATC + kt * 32 + koff];
        acc = __builtin_amdgcn_mfma_f32_16x16x32_bf16(a2[kt], b, acc, 0, 0, 0);
      }
      float bv = b2[nt * 16 + nlo];
      #pragma unroll
      for (int rg = 0; rg < 4; ++rg) {
        int m = wv * 16 + (lane >> 4) * 4 + rg;
        float hv = fmaxf(acc[rg] + bv, 0.0f);
        h2[m * H2STR + nt * 16 + nlo] = f2bf(hv);
      }
    }
    __syncthreads();

    // ---- layer 3 (128 -> 3) + sigmoid + in-wave weighted reduce ----
    if (wv < 3) {
      int j = wv, pp = lane;
      const unsigned short* h2row = h2 + pp * H2STR;
      float sum = b3[j];
      #pragma unroll
      for (int k = 0; k < FEATC; k += 4) {
        ushort4 hv = *(const ushort4*)&h2row[k];
        sum += bf2f(hv.x) * w3[(k+0)*3 + j] + bf2f(hv.y) * w3[(k+1)*3 + j]
             + bf2f(hv.z) * w3[(k+2)*3 + j] + bf2f(hv.w) * w3[(k+3)*3 + j];
      }
      float val = (1.0f / (1.0f + __expf(-sum))) * weights_ws[gp0 + pp];
      #pragma unroll
      for (int d = 32; d; d >>= 1) val += __shfl_xor(val, d);
      if (pp == 0) atomicAdd(&rgb_accum[r * 3 + j], val);
    }
  }
}

__global__ void finish_kernel(const float* __restrict__ rgb_accum,
                              const float* __restrict__ acc_ws,
                              float* __restrict__ out) {
  int i = blockIdx.x * blockDim.x + threadIdx.x;
  if (i < N_RAYS * 3) {
    int r = i / 3;
    float v = rgb_accum[i] + 1.0f - acc_ws[r];
    out[i] = fminf(fmaxf(v, 0.0f), 1.0f);
  }
}

extern "C" void kernel_launch(void* const* d_in, const int* in_sizes, int n_in,
                              void* d_out, int out_size, void* d_ws, size_t ws_size,
                              hipStream_t stream) {
  const float* rays_o = (const float*)d_in[0];
  const float* rays_d = (const float*)d_in[1];
  const float* dvol   = (const float*)d_in[2];
  const float* avol   = (const float*)d_in[3];
  const float* w1     = (const float*)d_in[4];
  const float* b1     = (const float*)d_in[5];
  const float* w2     = (const float*)d_in[6];
  const float* b2     = (const float*)d_in[7];
  const float* w3     = (const float*)d_in[8];
  const float* b3     = (const float*)d_in[9];
  float* out = (float*)d_out;

  float* weights_ws = (float*)d_ws;                         // NPTS
  float* acc_ws     = weights_ws + NPTS;                    // 2048
  float* rgb_accum  = acc_ws + N_RAYS;                      // 6144
  int*   count      = (int*)(rgb_accum + N_RAYS * 3);       // 1
  int*   work_ctr   = count + 1;                            // 1
  int*   bounds     = work_ctr + 1;                         // 6
  int*   worklist   = bounds + 6;                           // NCHUNK
  unsigned short* w1T = (unsigned short*)(worklist + NCHUNK);
  unsigned short* w2T = w1T + 128 * K1PAD;
  float* dvolT = (float*)(w2T + 128 * 128);                 // G3 f32
  unsigned short* appT = (unsigned short*)(dvolT + G3);     // G3*28 bf16

  size_t fixed_bytes = (size_t)(NPTS + N_RAYS + N_RAYS * 3 + 8 + NCHUNK) * 4
                     + (size_t)(128 * K1PAD + 128 * 128) * 2;
  bool usedt = ws_size >= fixed_bytes + (size_t)G3 * 4;
  bool uset  = ws_size >= fixed_bytes + (size_t)G3 * 4 + (size_t)G3 * CHP * 2;

  // zero rgb_accum + count + work_ctr; bounds mins -> large, maxs -> 0
  hipMemsetAsync(rgb_accum, 0, (N_RAYS * 3 + 2) * sizeof(float), stream);
  hipMemsetAsync(bounds, 0x7f, 3 * sizeof(int), stream);
  hipMemsetAsync(bounds + 3, 0, 3 * sizeof(int), stream);
  prep_weights<<<(128 * K1PAD + 128 * 128 + 255) / 256, 256, 0, stream>>>(w1, w2, w1T, w2T);
  if (usedt) {
    dvol_transpose<<<2048, 256, 0, stream>>>(dvol, dvolT);
    ray_kernel<true><<<N_RAYS, 256, 0, stream>>>(rays_o, rays_d, dvolT, weights_ws, acc_ws,
                                                 count, worklist, bounds);
  } else {
    ray_kernel<false><<<N_RAYS, 256, 0, stream>>>(rays_o, rays_d, dvol, weights_ws, acc_ws,
                                                  count, worklist, bounds);
  }
  if (uset) {
    transpose_kernel<<<G3 / 512, 256, 0, stream>>>(avol, appT, bounds);
    shade_kernel<true><<<1024, 256, 0, stream>>>(rays_o, rays_d, avol, appT, w1T, w2T,
                                                 b1, b2, w3, b3, weights_ws, rgb_accum,
                                                 count, work_ctr, worklist);
  } else {
    shade_kernel<false><<<1024, 256, 0, stream>>>(rays_o, rays_d, avol, appT, w1T, w2T,
                                                  b1, b2, w3, b3, weights_ws, rgb_accum,
                                                  count, work_ctr, worklist);
  }
  finish_kernel<<<(N_RAYS * 3 + 255) / 256, 256, 0, stream>>>(rgb_accum, acc_ws, out);
}

// Round 6
// 466.834 us; speedup vs baseline: 1.3529x; 1.3529x over previous
//
#include <hip/hip_runtime.h>
#include <math.h>
#include <limits.h>

#define N_RAYS 2048
#define NSAMP  256
#define NPTS   (N_RAYS * NSAMP)
#define NCHUNK (NPTS / 64)
#define GRIDN  128
#define G2     (GRIDN * GRIDN)
#define G3     (GRIDN * GRIDN * GRIDN)
#define APPC   27
#define CHP    28            // padded channels in transposed volume
#define FEATC  128
#define K1PAD  160           // 150 padded to 160 (5 k-tiles of 32)
#define ASTR   168           // A_lds k-stride
#define HSTR   136           // h1_lds k-stride
#define H2STR  130           // h2 stride (aliases A_lds) — odd dword stride: conflict-free

typedef __attribute__((ext_vector_type(8))) short short8;
typedef __attribute__((ext_vector_type(4))) float float4v;

__device__ __forceinline__ unsigned short f2bf(float f) {
  unsigned int u = __float_as_uint(f);
  return (unsigned short)((u + 0x7FFFu + ((u >> 16) & 1u)) >> 16);
}
__device__ __forceinline__ float bf2f(unsigned short u) {
  return __uint_as_float(((unsigned int)u) << 16);
}

__device__ __forceinline__ void grid_coords(float cx, float cy, float cz,
                                            int& x0, int& y0, int& z0,
                                            float& fx, float& fy, float& fz) {
  float x = (cx + 1.0f) * 0.5f * 127.0f;
  float y = (cy + 1.0f) * 0.5f * 127.0f;
  float z = (cz + 1.0f) * 0.5f * 127.0f;
  float x0f = fminf(fmaxf(floorf(x), 0.0f), 126.0f);
  float y0f = fminf(fmaxf(floorf(y), 0.0f), 126.0f);
  float z0f = fminf(fmaxf(floorf(z), 0.0f), 126.0f);
  x0 = (int)x0f; y0 = (int)y0f; z0 = (int)z0f;
  fx = x - x0f; fy = y - y0f; fz = z - z0f;
}

// ---------------- density transpose: [z][y][x] -> [x][y][z] (32x32 LDS tiles per y)
__global__ __launch_bounds__(256)
void dvol_transpose(const float* __restrict__ dvol, float* __restrict__ dvolT) {
  __shared__ float tile[32][33];
  int y  = blockIdx.x & 127;
  int zt = ((blockIdx.x >> 7) & 3) * 32;
  int xt = (blockIdx.x >> 9) * 32;
  int tx = threadIdx.x & 31;
  int r0 = threadIdx.x >> 5;       // 0..7
  #pragma unroll
  for (int i = 0; i < 4; ++i) {
    int zr = r0 + i * 8;
    tile[zr][tx] = dvol[((zt + zr) * GRIDN + y) * GRIDN + xt + tx];
  }
  __syncthreads();
  #pragma unroll
  for (int i = 0; i < 4; ++i) {
    int xr = r0 + i * 8;
    dvolT[((xt + xr) * GRIDN + y) * GRIDN + zt + tx] = tile[tx][xr];
  }
}

// ---------------- ray kernel: alpha + wave-scan cumprod -> weights, acc,
// per-chunk live flags + per-ray AABB (NO global atomics)
template <bool TRANS>
__global__ __launch_bounds__(256)
void ray_kernel(const float* __restrict__ rays_o, const float* __restrict__ rays_d,
                const float* __restrict__ dvol,     // [z][y][x] (TRANS=0) or [x][y][z] (TRANS=1)
                float* __restrict__ weights_ws, float* __restrict__ acc_ws,
                int* __restrict__ live_flags, int* __restrict__ block_bounds) {
  int r = blockIdx.x, s = threadIdx.x;
  int lane = s & 63, wv = s >> 6;
  float ox = rays_o[r*3+0], oy = rays_o[r*3+1], oz = rays_o[r*3+2];
  float dx = rays_d[r*3+0], dy = rays_d[r*3+1], dz = rays_d[r*3+2];
  float inv = rsqrtf(dx*dx + dy*dy + dz*dz);
  dx *= inv; dy *= inv; dz *= inv;
  float z = 2.0f + (4.0f / 255.0f) * (float)s;
  float px = ox + dx * z, py = oy + dy * z, pz = oz + dz * z;
  float cx = fminf(fmaxf((px + 1.5f) * (2.0f/3.0f) - 1.0f, -1.0f), 1.0f);
  float cy = fminf(fmaxf((py + 1.5f) * (2.0f/3.0f) - 1.0f, -1.0f), 1.0f);
  float cz = fminf(fmaxf((pz + 1.5f) * (2.0f/3.0f) - 1.0f, -1.0f), 1.0f);
  int x0, y0, z0; float fx, fy, fz;
  grid_coords(cx, cy, cz, x0, y0, z0, fx, fy, fz);
  float gx = 1.0f - fx, gy = 1.0f - fy, gz = 1.0f - fz;
  float sf;
  if (TRANS) {
    int base = (x0 * GRIDN + y0) * GRIDN + z0;
    float v000 = dvol[base],            v001 = dvol[base + 1];
    float v010 = dvol[base + GRIDN],    v011 = dvol[base + GRIDN + 1];
    float v100 = dvol[base + G2],       v101 = dvol[base + G2 + 1];
    float v110 = dvol[base + G2+GRIDN], v111 = dvol[base + G2+GRIDN+1];
    float c00 = gz * v000 + fz * v001;
    float c01 = gz * v010 + fz * v011;
    float c10 = gz * v100 + fz * v101;
    float c11 = gz * v110 + fz * v111;
    sf = gx * (gy * c00 + fy * c01) + fx * (gy * c10 + fy * c11);
  } else {
    int base = (z0 * GRIDN + y0) * GRIDN + x0;
    sf = dvol[base]            * (gz*gy*gx) + dvol[base + 1]            * (gz*gy*fx)
       + dvol[base + GRIDN]    * (gz*fy*gx) + dvol[base + GRIDN + 1]    * (gz*fy*fx)
       + dvol[base + G2]       * (fz*gy*gx) + dvol[base + G2 + 1]       * (fz*gy*fx)
       + dvol[base + G2+GRIDN] * (fz*fy*gx) + dvol[base + G2+GRIDN+1]   * (fz*fy*fx);
  }
  float xv = sf - 10.0f;
  float sp = fmaxf(xv, 0.0f) + __logf(1.0f + __expf(-fabsf(xv)));
  float alpha = 1.0f - __expf(-sp * (100.0f / 255.0f));

  // wave-level inclusive prefix product of (1 - a + 1e-10)
  float tt = 1.0f - alpha + 1e-10f;
  float p = tt;
  #pragma unroll
  for (int d = 1; d < 64; d <<= 1) {
    float v = __shfl_up(p, d);
    if (lane >= d) p *= v;
  }
  __shared__ float wtot[4], wacc[4];
  __shared__ int s_mn[4][3], s_mx[4][3], s_live[4];
  if (lane == 63) wtot[wv] = p;
  __syncthreads();
  float pref = 1.0f;
  #pragma unroll
  for (int w2i = 0; w2i < 3; ++w2i) if (w2i < wv) pref *= wtot[w2i];
  float ex = __shfl_up(p, 1);
  if (lane == 0) ex = 1.0f;
  float T = pref * ex;
  float wgt = alpha * T;
  weights_ws[r * NSAMP + s] = wgt;

  // wave reduce: weight sum; AABB from endpoint lanes (coords monotone along ray)
  float sum = wgt;
  #pragma unroll
  for (int d = 32; d; d >>= 1) sum += __shfl_xor(sum, d);
  int xa = __shfl(x0, 0), xb = __shfl(x0, 63);
  int ya = __shfl(y0, 0), yb = __shfl(y0, 63);
  int za = __shfl(z0, 0), zb = __shfl(z0, 63);
  if (lane == 0) {
    wacc[wv] = sum;
    int live = (sum >= 1e-5f) ? 1 : 0;
    live_flags[r * 4 + wv] = live;
    s_live[wv] = live;
    s_mn[wv][0] = min(xa, xb); s_mx[wv][0] = max(xa, xb);
    s_mn[wv][1] = min(ya, yb); s_mx[wv][1] = max(ya, yb);
    s_mn[wv][2] = min(za, zb); s_mx[wv][2] = max(za, zb);
  }
  __syncthreads();
  if (s == 0) {
    acc_ws[r] = wacc[0] + wacc[1] + wacc[2] + wacc[3];
    int mn[3] = {INT_MAX, INT_MAX, INT_MAX};
    int mx[3] = {-1, -1, -1};
    #pragma unroll
    for (int w = 0; w < 4; ++w) {
      if (s_live[w]) {
        #pragma unroll
        for (int i = 0; i < 3; ++i) {
          mn[i] = min(mn[i], s_mn[w][i]);
          mx[i] = max(mx[i], s_mx[w][i]);
        }
      }
    }
    block_bounds[r*6+0] = mn[0]; block_bounds[r*6+1] = mn[1]; block_bounds[r*6+2] = mn[2];
    block_bounds[r*6+3] = mx[0] + 1; block_bounds[r*6+4] = mx[1] + 1; block_bounds[r*6+5] = mx[2] + 1;
  }
}

// ---------------- compact: flags -> worklist (1 atomic/block) + bounds reduce
__global__ __launch_bounds__(256)
void compact_kernel(const int* __restrict__ live_flags, const int* __restrict__ block_bounds,
                    int* __restrict__ count, int* __restrict__ worklist,
                    int* __restrict__ bounds) {
  int t = threadIdx.x;
  int id = blockIdx.x * 256 + t;
  int lane = t & 63, wv = t >> 6;
  int flag = live_flags[id];
  unsigned long long m = __ballot(flag != 0);
  int prefix = __popcll(m & ((1ull << lane) - 1ull));
  int wcount = __popcll(m);
  __shared__ int wbase[4];
  if (lane == 0) wbase[wv] = wcount;
  __syncthreads();
  if (t == 0) {
    int tot = wbase[0] + wbase[1] + wbase[2] + wbase[3];
    int base = atomicAdd(count, tot);
    #pragma unroll
    for (int w = 0; w < 4; ++w) { int c = wbase[w]; wbase[w] = base; base += c; }
  }
  __syncthreads();
  if (flag) worklist[wbase[wv] + prefix] = id;

  // bounds: 64 ray-rows per block (2048 rays / 32 blocks)
  if (t < 64) {
    int rr = blockIdx.x * 64 + t;
    int mn0 = block_bounds[rr*6+0], mn1 = block_bounds[rr*6+1], mn2 = block_bounds[rr*6+2];
    int mx0 = block_bounds[rr*6+3], mx1 = block_bounds[rr*6+4], mx2 = block_bounds[rr*6+5];
    #pragma unroll
    for (int d = 32; d; d >>= 1) {
      mn0 = min(mn0, __shfl_xor(mn0, d)); mx0 = max(mx0, __shfl_xor(mx0, d));
      mn1 = min(mn1, __shfl_xor(mn1, d)); mx1 = max(mx1, __shfl_xor(mx1, d));
      mn2 = min(mn2, __shfl_xor(mn2, d)); mx2 = max(mx2, __shfl_xor(mx2, d));
    }
    if (t == 0) {
      atomicMin(&bounds[0], mn0); atomicMax(&bounds[3], mx0);
      atomicMin(&bounds[1], mn1); atomicMax(&bounds[4], mx1);
      atomicMin(&bounds[2], mn2); atomicMax(&bounds[5], mx2);
    }
  }
}

// ---------------- transpose app volume (AABB-restricted):
// [27][z][y][x] f32 -> [z][y][x][28] bf16, 2 voxels per thread
__global__ __launch_bounds__(256)
void transpose_kernel(const float* __restrict__ avol, unsigned short* __restrict__ appT,
                      const int* __restrict__ bounds) {
  int vblk = blockIdx.x * 512;            // block covers one z, 4 y-rows
  int zb = vblk >> 14;
  int yb = (vblk & 16383) >> 7;           // block covers y in [yb, yb+3]
  int zmin = bounds[2], zmax = bounds[5];
  int ymin = bounds[1], ymax = bounds[4];
  if (zb < zmin || zb > zmax) return;
  if (yb + 3 < ymin || yb > ymax) return;
  int v0 = vblk + threadIdx.x * 2;
  int y = (v0 & 16383) >> 7;
  int x = v0 & 127;
  if (y < ymin || y > ymax) return;
  int xmin = bounds[0], xmax = bounds[3];
  if (x + 1 < xmin || x > xmax) return;

  float2 v[APPC];
  #pragma unroll
  for (int c = 0; c < APPC; ++c) v[c] = *(const float2*)&avol[(size_t)c * G3 + v0];
  unsigned short* dst = appT + (size_t)v0 * CHP;
  #pragma unroll
  for (int i = 0; i < 7; ++i) {
    ushort4 o;
    o.x = f2bf(v[4*i+0].x); o.y = f2bf(v[4*i+1].x);
    o.z = (4*i+2 < APPC) ? f2bf(v[4*i+2].x) : (unsigned short)0;
    o.w = (4*i+3 < APPC) ? f2bf(v[4*i+3].x) : (unsigned short)0;
    *(ushort4*)&dst[4*i] = o;
  }
  #pragma unroll
  for (int i = 0; i < 7; ++i) {
    ushort4 o;
    o.x = f2bf(v[4*i+0].y); o.y = f2bf(v[4*i+1].y);
    o.z = (4*i+2 < APPC) ? f2bf(v[4*i+2].y) : (unsigned short)0;
    o.w = (4*i+3 < APPC) ? f2bf(v[4*i+3].y) : (unsigned short)0;
    *(ushort4*)&dst[CHP + 4*i] = o;
  }
}

// ---------------- weight prep
__global__ __launch_bounds__(256)
void prep_weights(const float* __restrict__ w1, const float* __restrict__ w2,
                  unsigned short* __restrict__ w1T, unsigned short* __restrict__ w2T) {
  int t = blockIdx.x * 256 + threadIdx.x;
  if (t < 128 * K1PAD) {
    int n = t / K1PAD, k = t - n * K1PAD;
    w1T[t] = (k < 150) ? f2bf(w1[k * 128 + n]) : (unsigned short)0;
  } else {
    int i = t - 128 * K1PAD;
    if (i < 128 * 128) {
      int n = i >> 7, k = i & 127;
      w2T[i] = f2bf(w2[k * 128 + n]);
    }
  }
}

// ---------------- persistent shade over compacted worklist
template <bool USET>
__global__ __launch_bounds__(256)
void shade_kernel(const float* __restrict__ rays_o, const float* __restrict__ rays_d,
                  const float* __restrict__ avol, const unsigned short* __restrict__ appT,
                  const unsigned short* __restrict__ w1T, const unsigned short* __restrict__ w2T,
                  const float* __restrict__ b1, const float* __restrict__ b2,
                  const float* __restrict__ w3, const float* __restrict__ b3,
                  const float* __restrict__ weights_ws, float* __restrict__ rgb_accum,
                  const int* __restrict__ count, int* __restrict__ work_ctr,
                  const int* __restrict__ worklist) {
  __shared__ unsigned short A_lds[64 * ASTR];   // reused as h2 (stride 130)
  __shared__ unsigned short h1_lds[64 * HSTR];
  __shared__ int s_idx, s_n;

  int t = threadIdx.x;
  int lane = t & 63, wv = t >> 6;

  if (t == 0) s_n = *count;

  for (;;) {
    __syncthreads();
    if (t == 0) s_idx = atomicAdd(work_ctr, 1);
    __syncthreads();
    if (s_idx >= s_n) break;
    int chunk = worklist[s_idx];
    int gp0 = chunk * 64;
    int r = gp0 >> 8;

    // ---- gather + positional encoding ----
    {
      int q = t & 3, pt = t >> 2;
      int gp = gp0 + pt, s = gp & 255;
      float ox = rays_o[r*3+0], oy = rays_o[r*3+1], oz = rays_o[r*3+2];
      float dx = rays_d[r*3+0], dy = rays_d[r*3+1], dz = rays_d[r*3+2];
      float inv = rsqrtf(dx*dx + dy*dy + dz*dz);
      dx *= inv; dy *= inv; dz *= inv;
      float z = 2.0f + (4.0f / 255.0f) * (float)s;
      float px = ox + dx * z, py = oy + dy * z, pz = oz + dz * z;
      float cx = fminf(fmaxf((px + 1.5f) * (2.0f/3.0f) - 1.0f, -1.0f), 1.0f);
      float cy = fminf(fmaxf((py + 1.5f) * (2.0f/3.0f) - 1.0f, -1.0f), 1.0f);
      float cz = fminf(fmaxf((pz + 1.5f) * (2.0f/3.0f) - 1.0f, -1.0f), 1.0f);
      int x0, y0, z0; float fxg, fyg, fzg;
      grid_coords(cx, cy, cz, x0, y0, z0, fxg, fyg, fzg);
      float gxg = 1.0f - fxg, gyg = 1.0f - fyg, gzg = 1.0f - fzg;
      float w8[8];
      w8[0] = gzg*gyg*gxg; w8[1] = gzg*gyg*fxg;
      w8[2] = gzg*fyg*gxg; w8[3] = gzg*fyg*fxg;
      w8[4] = fzg*gyg*gxg; w8[5] = fzg*gyg*fxg;
      w8[6] = fzg*fyg*gxg; w8[7] = fzg*fyg*fxg;
      int ibase = (z0 * GRIDN + y0) * GRIDN + x0;

      int vi = ibase + (q >> 1) * G2 + (q & 1) * GRIDN;
      float wA = w8[2*q], wB = w8[2*q+1];
      float part[27];
      if (USET) {
        const ushort4* c0 = (const ushort4*)(appT + (size_t)vi * CHP);
        const ushort4* c1 = (const ushort4*)(appT + (size_t)(vi + 1) * CHP);
        ushort4 a[7], b[7];
        #pragma unroll
        for (int i = 0; i < 7; ++i) { a[i] = c0[i]; b[i] = c1[i]; }
        #pragma unroll
        for (int c = 0; c < 27; ++c) {
          unsigned short ua = (&a[c >> 2].x)[c & 3];
          unsigned short ub = (&b[c >> 2].x)[c & 3];
          part[c] = wA * bf2f(ua) + wB * bf2f(ub);
        }
      } else {
        #pragma unroll
        for (int c = 0; c < 27; ++c) {
          const float* base = avol + (size_t)c * G3 + vi;
          part[c] = wA * base[0] + wB * base[1];
        }
      }
      #pragma unroll
      for (int c = 0; c < 27; ++c) {
        float v = part[c];
        v += __shfl_xor(v, 1);
        v += __shfl_xor(v, 2);
        part[c] = v;
      }
      float f[7];
      #pragma unroll
      for (int j = 0; j < 7; ++j) {
        float vlo = (q & 1) ? part[7 + j] : part[j];
        float vhi = (q & 1) ? part[(21 + j < 27) ? 21 + j : 26] : part[14 + j];
        f[j] = (q & 2) ? vhi : vlo;
      }
      unsigned short* Arow = A_lds + pt * ASTR;
      int cbase = 7 * q;
      #pragma unroll
      for (int j = 0; j < 7; ++j) {
        int c = cbase + j;
        if (c < 27) {
          float fv = f[j];
          Arow[c] = f2bf(fv);
          float s1 = __sinf(fv),      c1 = __cosf(fv);
          float s2 = __sinf(2.0f*fv), c2 = __cosf(2.0f*fv);
          Arow[30 + 2*c] = f2bf(s1); Arow[31 + 2*c] = f2bf(s2);
          Arow[84 + 2*c] = f2bf(c1); Arow[85 + 2*c] = f2bf(c2);
        }
      }
      if (q == 3) {
        float vd[3] = {dx, dy, dz};
        #pragma unroll
        for (int d = 0; d < 3; ++d) {
          Arow[27 + d] = f2bf(vd[d]);
          float s1 = __sinf(vd[d]),      c1 = __cosf(vd[d]);
          float s2 = __sinf(2.0f*vd[d]), c2 = __cosf(2.0f*vd[d]);
          Arow[138 + 2*d] = f2bf(s1); Arow[139 + 2*d] = f2bf(s2);
          Arow[144 + 2*d] = f2bf(c1); Arow[145 + 2*d] = f2bf(c2);
        }
      }
      if (q == 1) {
        #pragma unroll
        for (int i = 0; i < 5; ++i) *(unsigned int*)&Arow[150 + 2*i] = 0u;
      }
    }
    __syncthreads();

    // ---- MFMA MLP ----
    int nlo = lane & 15;
    int koff = (lane >> 4) * 8;
    int mrow = wv * 16 + nlo;

    short8 a1[5];
    #pragma unroll
    for (int kt = 0; kt < 5; ++kt)
      a1[kt] = *(const short8*)&A_lds[mrow * ASTR + kt * 32 + koff];
    #pragma unroll
    for (int nt = 0; nt < 8; ++nt) {
      float4v acc = {0.f, 0.f, 0.f, 0.f};
      #pragma unroll
      for (int kt = 0; kt < 5; ++kt) {
        short8 b = *(const short8*)&w1T[(nt * 16 + nlo) * K1PAD + kt * 32 + koff];
        acc = __builtin_amdgcn_mfma_f32_16x16x32_bf16(a1[kt], b, acc, 0, 0, 0);
      }
      float bv = b1[nt * 16 + nlo];
      #pragma unroll
      for (int rg = 0; rg < 4; ++rg) {
        int m = wv * 16 + (lane >> 4) * 4 + rg;
        float hv = fmaxf(acc[rg] + bv, 0.0f);
        h1_lds[m * HSTR + nt * 16 + nlo] = f2bf(hv);
      }
    }
    __syncthreads();

    short8 a2[4];
    #pragma unroll
    for (int kt = 0; kt < 4; ++kt)
      a2[kt] = *(const short8*)&h1_lds[mrow * HSTR + kt * 32 + koff];
    unsigned short* h2 = A_lds;
    #pragma unroll
    for (int nt = 0; nt < 8; ++nt) {
      float4v acc = {0.f, 0.f, 0.f, 0.f};
      #pragma unroll
      for (int kt = 0; kt < 4; ++kt) {
        short8 b = *(const short8*)&w2T[(nt * 16 + nlo) * FEATC + kt * 32 + koff];
        acc = __builtin_amdgcn_mfma_f32_16x16x32_bf16(a2[kt], b, acc, 0, 0, 0);
      }
      float bv = b2[nt * 16 + nlo];
      #pragma unroll
      for (int rg = 0; rg < 4; ++rg) {
        int m = wv * 16 + (lane >> 4) * 4 + rg;
        float hv = fmaxf(acc[rg] + bv, 0.0f);
        h2[m * H2STR + nt * 16 + nlo] = f2bf(hv);
      }
    }
    __syncthreads();

    // ---- layer 3 (128 -> 3) + sigmoid + in-wave weighted reduce ----
    if (wv < 3) {
      int j = wv, pp = lane;
      const unsigned short* h2row = h2 + pp * H2STR;
      float sum = b3[j];
      #pragma unroll
      for (int k = 0; k < FEATC; k += 4) {
        ushort4 hv = *(const ushort4*)&h2row[k];
        sum += bf2f(hv.x) * w3[(k+0)*3 + j] + bf2f(hv.y) * w3[(k+1)*3 + j]
             + bf2f(hv.z) * w3[(k+2)*3 + j] + bf2f(hv.w) * w3[(k+3)*3 + j];
      }
      float val = (1.0f / (1.0f + __expf(-sum))) * weights_ws[gp0 + pp];
      #pragma unroll
      for (int d = 32; d; d >>= 1) val += __shfl_xor(val, d);
      if (pp == 0) atomicAdd(&rgb_accum[r * 3 + j], val);
    }
  }
}

__global__ void finish_kernel(const float* __restrict__ rgb_accum,
                              const float* __restrict__ acc_ws,
                              float* __restrict__ out) {
  int i = blockIdx.x * blockDim.x + threadIdx.x;
  if (i < N_RAYS * 3) {
    int r = i / 3;
    float v = rgb_accum[i] + 1.0f - acc_ws[r];
    out[i] = fminf(fmaxf(v, 0.0f), 1.0f);
  }
}

extern "C" void kernel_launch(void* const* d_in, const int* in_sizes, int n_in,
                              void* d_out, int out_size, void* d_ws, size_t ws_size,
                              hipStream_t stream) {
  const float* rays_o = (const float*)d_in[0];
  const float* rays_d = (const float*)d_in[1];
  const float* dvol   = (const float*)d_in[2];
  const float* avol   = (const float*)d_in[3];
  const float* w1     = (const float*)d_in[4];
  const float* b1     = (const float*)d_in[5];
  const float* w2     = (const float*)d_in[6];
  const float* b2     = (const float*)d_in[7];
  const float* w3     = (const float*)d_in[8];
  const float* b3     = (const float*)d_in[9];
  float* out = (float*)d_out;

  float* weights_ws = (float*)d_ws;                         // NPTS
  float* acc_ws     = weights_ws + NPTS;                    // 2048
  float* rgb_accum  = acc_ws + N_RAYS;                      // 6144
  int*   count      = (int*)(rgb_accum + N_RAYS * 3);       // 1
  int*   work_ctr   = count + 1;                            // 1
  int*   bounds     = work_ctr + 1;                         // 6
  int*   worklist   = bounds + 6;                           // NCHUNK
  int*   live_flags = worklist + NCHUNK;                    // NCHUNK
  int*   block_bounds = live_flags + NCHUNK;                // N_RAYS*6
  unsigned short* w1T = (unsigned short*)(block_bounds + N_RAYS * 6);
  unsigned short* w2T = w1T + 128 * K1PAD;
  float* dvolT = (float*)(w2T + 128 * 128);                 // G3 f32
  unsigned short* appT = (unsigned short*)(dvolT + G3);     // G3*28 bf16

  size_t fixed_bytes = (size_t)(NPTS + N_RAYS + N_RAYS * 3 + 8 + 2 * NCHUNK + N_RAYS * 6) * 4
                     + (size_t)(128 * K1PAD + 128 * 128) * 2;
  bool usedt = ws_size >= fixed_bytes + (size_t)G3 * 4;
  bool uset  = ws_size >= fixed_bytes + (size_t)G3 * 4 + (size_t)G3 * CHP * 2;

  // zero rgb_accum + count + work_ctr; bounds mins -> large, maxs -> 0
  hipMemsetAsync(rgb_accum, 0, (N_RAYS * 3 + 2) * sizeof(float), stream);
  hipMemsetAsync(bounds, 0x7f, 3 * sizeof(int), stream);
  hipMemsetAsync(bounds + 3, 0, 3 * sizeof(int), stream);
  prep_weights<<<(128 * K1PAD + 128 * 128 + 255) / 256, 256, 0, stream>>>(w1, w2, w1T, w2T);
  if (usedt) {
    dvol_transpose<<<2048, 256, 0, stream>>>(dvol, dvolT);
    ray_kernel<true><<<N_RAYS, 256, 0, stream>>>(rays_o, rays_d, dvolT, weights_ws, acc_ws,
                                                 live_flags, block_bounds);
  } else {
    ray_kernel<false><<<N_RAYS, 256, 0, stream>>>(rays_o, rays_d, dvol, weights_ws, acc_ws,
                                                  live_flags, block_bounds);
  }
  compact_kernel<<<NCHUNK / 256, 256, 0, stream>>>(live_flags, block_bounds,
                                                   count, worklist, bounds);
  if (uset) {
    transpose_kernel<<<G3 / 512, 256, 0, stream>>>(avol, appT, bounds);
    shade_kernel<true><<<1024, 256, 0, stream>>>(rays_o, rays_d, avol, appT, w1T, w2T,
                                                 b1, b2, w3, b3, weights_ws, rgb_accum,
                                                 count, work_ctr, worklist);
  } else {
    shade_kernel<false><<<1024, 256, 0, stream>>>(rays_o, rays_d, avol, appT, w1T, w2T,
                                                  b1, b2, w3, b3, weights_ws, rgb_accum,
                                                  count, work_ctr, worklist);
  }
  finish_kernel<<<(N_RAYS * 3 + 255) / 256, 256, 0, stream>>>(rgb_accum, acc_ws, out);
}

// Round 7
// 445.780 us; speedup vs baseline: 1.4168x; 1.0472x over previous
//
#include <hip/hip_runtime.h>
#include <math.h>
#include <limits.h>

#define N_RAYS 2048
#define NSAMP  256
#define NPTS   (N_RAYS * NSAMP)
#define GRIDN  128
#define G2     (GRIDN * GRIDN)
#define G3     (GRIDN * GRIDN * GRIDN)
#define APPC   27
#define CHP    28            // padded channels in transposed volume
#define FEATC  128
#define K1PAD  160           // 150 padded to 160 (5 k-tiles of 32)
#define ASTR   168           // A_lds k-stride
#define HSTR   136           // h1_lds k-stride
#define H2STR  130           // h2 stride (aliases A_lds) — odd dword stride: conflict-free
#define WTH    1e-7f         // per-sample weight threshold

typedef __attribute__((ext_vector_type(8))) short short8;
typedef __attribute__((ext_vector_type(4))) float float4v;

__device__ __forceinline__ unsigned short f2bf(float f) {
  unsigned int u = __float_as_uint(f);
  return (unsigned short)((u + 0x7FFFu + ((u >> 16) & 1u)) >> 16);
}
__device__ __forceinline__ float bf2f(unsigned short u) {
  return __uint_as_float(((unsigned int)u) << 16);
}

__device__ __forceinline__ void grid_coords(float cx, float cy, float cz,
                                            int& x0, int& y0, int& z0,
                                            float& fx, float& fy, float& fz) {
  float x = (cx + 1.0f) * 0.5f * 127.0f;
  float y = (cy + 1.0f) * 0.5f * 127.0f;
  float z = (cz + 1.0f) * 0.5f * 127.0f;
  float x0f = fminf(fmaxf(floorf(x), 0.0f), 126.0f);
  float y0f = fminf(fmaxf(floorf(y), 0.0f), 126.0f);
  float z0f = fminf(fmaxf(floorf(z), 0.0f), 126.0f);
  x0 = (int)x0f; y0 = (int)y0f; z0 = (int)z0f;
  fx = x - x0f; fy = y - y0f; fz = z - z0f;
}

// ---------------- density transpose: [z][y][x] -> [x][y][z]
__global__ __launch_bounds__(256)
void dvol_transpose(const float* __restrict__ dvol, float* __restrict__ dvolT) {
  __shared__ float tile[32][33];
  int y  = blockIdx.x & 127;
  int zt = ((blockIdx.x >> 7) & 3) * 32;
  int xt = (blockIdx.x >> 9) * 32;
  int tx = threadIdx.x & 31;
  int r0 = threadIdx.x >> 5;
  #pragma unroll
  for (int i = 0; i < 4; ++i) {
    int zr = r0 + i * 8;
    tile[zr][tx] = dvol[((zt + zr) * GRIDN + y) * GRIDN + xt + tx];
  }
  __syncthreads();
  #pragma unroll
  for (int i = 0; i < 4; ++i) {
    int xr = r0 + i * 8;
    dvolT[((xt + xr) * GRIDN + y) * GRIDN + zt + tx] = tile[tx][xr];
  }
}

// ---------------- ray kernel: weights + per-wave live ballot + per-ray AABB (no atomics)
template <bool TRANS>
__global__ __launch_bounds__(256)
void ray_kernel(const float* __restrict__ rays_o, const float* __restrict__ rays_d,
                const float* __restrict__ dvol,
                float* __restrict__ weights_ws, float* __restrict__ acc_ws,
                unsigned long long* __restrict__ ray_mask, int* __restrict__ ray_count,
                int* __restrict__ block_bounds) {
  int r = blockIdx.x, s = threadIdx.x;
  int lane = s & 63, wv = s >> 6;
  float ox = rays_o[r*3+0], oy = rays_o[r*3+1], oz = rays_o[r*3+2];
  float dx = rays_d[r*3+0], dy = rays_d[r*3+1], dz = rays_d[r*3+2];
  float inv = rsqrtf(dx*dx + dy*dy + dz*dz);
  dx *= inv; dy *= inv; dz *= inv;
  float z = 2.0f + (4.0f / 255.0f) * (float)s;
  float px = ox + dx * z, py = oy + dy * z, pz = oz + dz * z;
  float cx = fminf(fmaxf((px + 1.5f) * (2.0f/3.0f) - 1.0f, -1.0f), 1.0f);
  float cy = fminf(fmaxf((py + 1.5f) * (2.0f/3.0f) - 1.0f, -1.0f), 1.0f);
  float cz = fminf(fmaxf((pz + 1.5f) * (2.0f/3.0f) - 1.0f, -1.0f), 1.0f);
  int x0, y0, z0; float fx, fy, fz;
  grid_coords(cx, cy, cz, x0, y0, z0, fx, fy, fz);
  float gx = 1.0f - fx, gy = 1.0f - fy, gz = 1.0f - fz;
  float sf;
  if (TRANS) {
    int base = (x0 * GRIDN + y0) * GRIDN + z0;
    float v000 = dvol[base],            v001 = dvol[base + 1];
    float v010 = dvol[base + GRIDN],    v011 = dvol[base + GRIDN + 1];
    float v100 = dvol[base + G2],       v101 = dvol[base + G2 + 1];
    float v110 = dvol[base + G2+GRIDN], v111 = dvol[base + G2+GRIDN+1];
    float c00 = gz * v000 + fz * v001;
    float c01 = gz * v010 + fz * v011;
    float c10 = gz * v100 + fz * v101;
    float c11 = gz * v110 + fz * v111;
    sf = gx * (gy * c00 + fy * c01) + fx * (gy * c10 + fy * c11);
  } else {
    int base = (z0 * GRIDN + y0) * GRIDN + x0;
    sf = dvol[base]            * (gz*gy*gx) + dvol[base + 1]            * (gz*gy*fx)
       + dvol[base + GRIDN]    * (gz*fy*gx) + dvol[base + GRIDN + 1]    * (gz*fy*fx)
       + dvol[base + G2]       * (fz*gy*gx) + dvol[base + G2 + 1]       * (fz*gy*fx)
       + dvol[base + G2+GRIDN] * (fz*fy*gx) + dvol[base + G2+GRIDN+1]   * (fz*fy*fx);
  }
  float xv = sf - 10.0f;
  float sp = fmaxf(xv, 0.0f) + __logf(1.0f + __expf(-fabsf(xv)));
  float alpha = 1.0f - __expf(-sp * (100.0f / 255.0f));

  // wave-level inclusive prefix product of (1 - a + 1e-10)
  float tt = 1.0f - alpha + 1e-10f;
  float p = tt;
  #pragma unroll
  for (int d = 1; d < 64; d <<= 1) {
    float v = __shfl_up(p, d);
    if (lane >= d) p *= v;
  }
  __shared__ float wtot[4], wacc[4];
  __shared__ int s_cnt[4], s_mn[4][3], s_mx[4][3], s_live[4];
  if (lane == 63) wtot[wv] = p;
  __syncthreads();
  float pref = 1.0f;
  #pragma unroll
  for (int w2i = 0; w2i < 3; ++w2i) if (w2i < wv) pref *= wtot[w2i];
  float ex = __shfl_up(p, 1);
  if (lane == 0) ex = 1.0f;
  float T = pref * ex;
  float wgt = alpha * T;
  weights_ws[r * NSAMP + s] = wgt;

  float sum = wgt;
  #pragma unroll
  for (int d = 32; d; d >>= 1) sum += __shfl_xor(sum, d);

  unsigned long long m = __ballot(wgt >= WTH);
  int xa = __shfl(x0, 0), xb = __shfl(x0, 63);
  int ya = __shfl(y0, 0), yb = __shfl(y0, 63);
  int za = __shfl(z0, 0), zb = __shfl(z0, 63);
  if (lane == 0) {
    wacc[wv] = sum;
    ray_mask[r * 4 + wv] = m;
    s_cnt[wv] = __popcll(m);
    s_live[wv] = (m != 0ull) ? 1 : 0;
    s_mn[wv][0] = min(xa, xb); s_mx[wv][0] = max(xa, xb);
    s_mn[wv][1] = min(ya, yb); s_mx[wv][1] = max(ya, yb);
    s_mn[wv][2] = min(za, zb); s_mx[wv][2] = max(za, zb);
  }
  __syncthreads();
  if (s == 0) {
    acc_ws[r] = wacc[0] + wacc[1] + wacc[2] + wacc[3];
    ray_count[r] = s_cnt[0] + s_cnt[1] + s_cnt[2] + s_cnt[3];
    int mn[3] = {INT_MAX, INT_MAX, INT_MAX};
    int mx[3] = {-1, -1, -1};
    #pragma unroll
    for (int w = 0; w < 4; ++w) {
      if (s_live[w]) {
        #pragma unroll
        for (int i = 0; i < 3; ++i) {
          mn[i] = min(mn[i], s_mn[w][i]);
          mx[i] = max(mx[i], s_mx[w][i]);
        }
      }
    }
    block_bounds[r*6+0] = mn[0]; block_bounds[r*6+1] = mn[1]; block_bounds[r*6+2] = mn[2];
    block_bounds[r*6+3] = mx[0] + 1; block_bounds[r*6+4] = mx[1] + 1; block_bounds[r*6+5] = mx[2] + 1;
  }
}

// ---------------- scan: ray_count -> ray_base (exclusive), total, AABB, work_ctr=0
__global__ __launch_bounds__(256)
void scan_kernel(const int* __restrict__ ray_count, const int* __restrict__ block_bounds,
                 int* __restrict__ ray_base, int* __restrict__ count,
                 int* __restrict__ work_ctr, int* __restrict__ bounds) {
  int t = threadIdx.x, lane = t & 63, wv = t >> 6;
  int c[8], tsum = 0;
  #pragma unroll
  for (int j = 0; j < 8; ++j) { c[j] = ray_count[t*8+j]; tsum += c[j]; }
  int p = tsum;
  #pragma unroll
  for (int d = 1; d < 64; d <<= 1) { int v = __shfl_up(p, d); if (lane >= d) p += v; }
  __shared__ int wsum[4];
  if (lane == 63) wsum[wv] = p;
  __syncthreads();
  int pref = 0;
  #pragma unroll
  for (int w = 0; w < 3; ++w) if (w < wv) pref += wsum[w];
  int excl = pref + p - tsum;
  #pragma unroll
  for (int j = 0; j < 8; ++j) { ray_base[t*8+j] = excl; excl += c[j]; }
  if (t == 255) { count[0] = excl; work_ctr[0] = 0; }

  // AABB over live rays
  int mn0 = INT_MAX, mn1 = INT_MAX, mn2 = INT_MAX, mx0 = -1, mx1 = -1, mx2 = -1;
  #pragma unroll
  for (int j = 0; j < 8; ++j) {
    int r = t*8+j;
    if (c[j] > 0) {
      mn0 = min(mn0, block_bounds[r*6+0]); mx0 = max(mx0, block_bounds[r*6+3]);
      mn1 = min(mn1, block_bounds[r*6+1]); mx1 = max(mx1, block_bounds[r*6+4]);
      mn2 = min(mn2, block_bounds[r*6+2]); mx2 = max(mx2, block_bounds[r*6+5]);
    }
  }
  #pragma unroll
  for (int d = 32; d; d >>= 1) {
    mn0 = min(mn0, __shfl_xor(mn0, d)); mx0 = max(mx0, __shfl_xor(mx0, d));
    mn1 = min(mn1, __shfl_xor(mn1, d)); mx1 = max(mx1, __shfl_xor(mx1, d));
    mn2 = min(mn2, __shfl_xor(mn2, d)); mx2 = max(mx2, __shfl_xor(mx2, d));
  }
  __shared__ int bmn[4][3], bmx[4][3];
  if (lane == 0) {
    bmn[wv][0] = mn0; bmn[wv][1] = mn1; bmn[wv][2] = mn2;
    bmx[wv][0] = mx0; bmx[wv][1] = mx1; bmx[wv][2] = mx2;
  }
  __syncthreads();
  if (t == 0) {
    #pragma unroll
    for (int w = 1; w < 4; ++w) {
      #pragma unroll
      for (int i = 0; i < 3; ++i) {
        bmn[0][i] = min(bmn[0][i], bmn[w][i]);
        bmx[0][i] = max(bmx[0][i], bmx[w][i]);
      }
    }
    bounds[0] = bmn[0][0]; bounds[1] = bmn[0][1]; bounds[2] = bmn[0][2];
    bounds[3] = bmx[0][0]; bounds[4] = bmx[0][1]; bounds[5] = bmx[0][2];
  }
}

// ---------------- scatter: masks -> sorted sample list (wave per ray, no atomics)
__global__ __launch_bounds__(256)
void scatter_kernel(const unsigned long long* __restrict__ ray_mask,
                    const int* __restrict__ ray_base, int* __restrict__ sample_list) {
  int t = threadIdx.x, lane = t & 63, wv = t >> 6;
  int r = blockIdx.x * 4 + wv;
  int base = ray_base[r];
  int off = 0;
  #pragma unroll
  for (int w = 0; w < 4; ++w) {
    unsigned long long m = ray_mask[r * 4 + w];
    int flag = (int)((m >> lane) & 1ull);
    int pre = __popcll(m & ((1ull << lane) - 1ull));
    if (flag) sample_list[base + off + pre] = r * 256 + w * 64 + lane;
    off += __popcll(m);
  }
}

// ---------------- transpose app volume (AABB-restricted)
__global__ __launch_bounds__(256)
void transpose_kernel(const float* __restrict__ avol, unsigned short* __restrict__ appT,
                      const int* __restrict__ bounds) {
  int vblk = blockIdx.x * 512;
  int zb = vblk >> 14;
  int yb = (vblk & 16383) >> 7;
  int zmin = bounds[2], zmax = bounds[5];
  int ymin = bounds[1], ymax = bounds[4];
  if (zb < zmin || zb > zmax) return;
  if (yb + 3 < ymin || yb > ymax) return;
  int v0 = vblk + threadIdx.x * 2;
  int y = (v0 & 16383) >> 7;
  int x = v0 & 127;
  if (y < ymin || y > ymax) return;
  int xmin = bounds[0], xmax = bounds[3];
  if (x + 1 < xmin || x > xmax) return;

  float2 v[APPC];
  #pragma unroll
  for (int c = 0; c < APPC; ++c) v[c] = *(const float2*)&avol[(size_t)c * G3 + v0];
  unsigned short* dst = appT + (size_t)v0 * CHP;
  #pragma unroll
  for (int i = 0; i < 7; ++i) {
    ushort4 o;
    o.x = f2bf(v[4*i+0].x); o.y = f2bf(v[4*i+1].x);
    o.z = (4*i+2 < APPC) ? f2bf(v[4*i+2].x) : (unsigned short)0;
    o.w = (4*i+3 < APPC) ? f2bf(v[4*i+3].x) : (unsigned short)0;
    *(ushort4*)&dst[4*i] = o;
  }
  #pragma unroll
  for (int i = 0; i < 7; ++i) {
    ushort4 o;
    o.x = f2bf(v[4*i+0].y); o.y = f2bf(v[4*i+1].y);
    o.z = (4*i+2 < APPC) ? f2bf(v[4*i+2].y) : (unsigned short)0;
    o.w = (4*i+3 < APPC) ? f2bf(v[4*i+3].y) : (unsigned short)0;
    *(ushort4*)&dst[CHP + 4*i] = o;
  }
}

// ---------------- weight prep
__global__ __launch_bounds__(256)
void prep_weights(const float* __restrict__ w1, const float* __restrict__ w2,
                  unsigned short* __restrict__ w1T, unsigned short* __restrict__ w2T) {
  int t = blockIdx.x * 256 + threadIdx.x;
  if (t < 128 * K1PAD) {
    int n = t / K1PAD, k = t - n * K1PAD;
    w1T[t] = (k < 150) ? f2bf(w1[k * 128 + n]) : (unsigned short)0;
  } else {
    int i = t - 128 * K1PAD;
    if (i < 128 * 128) {
      int n = i >> 7, k = i & 127;
      w2T[i] = f2bf(w2[k * 128 + n]);
    }
  }
}

// ---------------- persistent shade over compacted SAMPLE list
template <bool USET>
__global__ __launch_bounds__(256)
void shade_kernel(const float* __restrict__ rays_o, const float* __restrict__ rays_d,
                  const float* __restrict__ avol, const unsigned short* __restrict__ appT,
                  const unsigned short* __restrict__ w1T, const unsigned short* __restrict__ w2T,
                  const float* __restrict__ b1, const float* __restrict__ b2,
                  const float* __restrict__ w3, const float* __restrict__ b3,
                  const float* __restrict__ weights_ws, float* __restrict__ rgb_pts,
                  const int* __restrict__ count, int* __restrict__ work_ctr,
                  const int* __restrict__ sample_list) {
  __shared__ unsigned short A_lds[64 * ASTR];   // reused as h2 (stride 130)
  __shared__ unsigned short h1_lds[64 * HSTR];
  __shared__ float wlds[64];
  __shared__ int s_idx, s_items, s_n;

  int t = threadIdx.x;
  int lane = t & 63, wv = t >> 6;

  if (t == 0) { s_n = *count; s_items = (s_n + 63) >> 6; }

  for (;;) {
    __syncthreads();
    if (t == 0) s_idx = atomicAdd(work_ctr, 1);
    __syncthreads();
    if (s_idx >= s_items) break;
    int base64 = s_idx * 64;
    int n = s_n;

    // ---- gather + positional encoding ----
    {
      int q = t & 3, pt = t >> 2;
      int i = base64 + pt;
      int id = (i < n) ? sample_list[i] : -1;
      int sid = max(id, 0);
      int r = sid >> 8, s = sid & 255;
      float ox = rays_o[r*3+0], oy = rays_o[r*3+1], oz = rays_o[r*3+2];
      float dx = rays_d[r*3+0], dy = rays_d[r*3+1], dz = rays_d[r*3+2];
      float inv = rsqrtf(dx*dx + dy*dy + dz*dz);
      dx *= inv; dy *= inv; dz *= inv;
      float z = 2.0f + (4.0f / 255.0f) * (float)s;
      float px = ox + dx * z, py = oy + dy * z, pz = oz + dz * z;
      float cx = fminf(fmaxf((px + 1.5f) * (2.0f/3.0f) - 1.0f, -1.0f), 1.0f);
      float cy = fminf(fmaxf((py + 1.5f) * (2.0f/3.0f) - 1.0f, -1.0f), 1.0f);
      float cz = fminf(fmaxf((pz + 1.5f) * (2.0f/3.0f) - 1.0f, -1.0f), 1.0f);
      int x0, y0, z0; float fxg, fyg, fzg;
      grid_coords(cx, cy, cz, x0, y0, z0, fxg, fyg, fzg);
      float gxg = 1.0f - fxg, gyg = 1.0f - fyg, gzg = 1.0f - fzg;
      float w8[8];
      w8[0] = gzg*gyg*gxg; w8[1] = gzg*gyg*fxg;
      w8[2] = gzg*fyg*gxg; w8[3] = gzg*fyg*fxg;
      w8[4] = fzg*gyg*gxg; w8[5] = fzg*gyg*fxg;
      w8[6] = fzg*fyg*gxg; w8[7] = fzg*fyg*fxg;
      int ibase = (z0 * GRIDN + y0) * GRIDN + x0;

      if (q == 0) wlds[pt] = (id >= 0) ? weights_ws[sid] : 0.0f;

      int vi = ibase + (q >> 1) * G2 + (q & 1) * GRIDN;
      float wA = w8[2*q], wB = w8[2*q+1];
      float part[27];
      if (USET) {
        const ushort4* c0 = (const ushort4*)(appT + (size_t)vi * CHP);
        const ushort4* c1 = (const ushort4*)(appT + (size_t)(vi + 1) * CHP);
        ushort4 a[7], b[7];
        #pragma unroll
        for (int i2 = 0; i2 < 7; ++i2) { a[i2] = c0[i2]; b[i2] = c1[i2]; }
        #pragma unroll
        for (int c = 0; c < 27; ++c) {
          unsigned short ua = (&a[c >> 2].x)[c & 3];
          unsigned short ub = (&b[c >> 2].x)[c & 3];
          part[c] = wA * bf2f(ua) + wB * bf2f(ub);
        }
      } else {
        #pragma unroll
        for (int c = 0; c < 27; ++c) {
          const float* bptr = avol + (size_t)c * G3 + vi;
          part[c] = wA * bptr[0] + wB * bptr[1];
        }
      }
      #pragma unroll
      for (int c = 0; c < 27; ++c) {
        float v = part[c];
        v += __shfl_xor(v, 1);
        v += __shfl_xor(v, 2);
        part[c] = v;
      }
      float f[7];
      #pragma unroll
      for (int j = 0; j < 7; ++j) {
        float vlo = (q & 1) ? part[7 + j] : part[j];
        float vhi = (q & 1) ? part[(21 + j < 27) ? 21 + j : 26] : part[14 + j];
        f[j] = (q & 2) ? vhi : vlo;
      }
      unsigned short* Arow = A_lds + pt * ASTR;
      int cbase = 7 * q;
      #pragma unroll
      for (int j = 0; j < 7; ++j) {
        int c = cbase + j;
        if (c < 27) {
          float fv = f[j];
          Arow[c] = f2bf(fv);
          float s1 = __sinf(fv),      c1 = __cosf(fv);
          float s2 = __sinf(2.0f*fv), c2 = __cosf(2.0f*fv);
          Arow[30 + 2*c] = f2bf(s1); Arow[31 + 2*c] = f2bf(s2);
          Arow[84 + 2*c] = f2bf(c1); Arow[85 + 2*c] = f2bf(c2);
        }
      }
      if (q == 3) {
        float vd[3] = {dx, dy, dz};
        #pragma unroll
        for (int d = 0; d < 3; ++d) {
          Arow[27 + d] = f2bf(vd[d]);
          float s1 = __sinf(vd[d]),      c1 = __cosf(vd[d]);
          float s2 = __sinf(2.0f*vd[d]), c2 = __cosf(2.0f*vd[d]);
          Arow[138 + 2*d] = f2bf(s1); Arow[139 + 2*d] = f2bf(s2);
          Arow[144 + 2*d] = f2bf(c1); Arow[145 + 2*d] = f2bf(c2);
        }
      }
      if (q == 1) {
        #pragma unroll
        for (int i2 = 0; i2 < 5; ++i2) *(unsigned int*)&Arow[150 + 2*i2] = 0u;
      }
    }
    __syncthreads();

    // ---- MFMA MLP ----
    int nlo = lane & 15;
    int koff = (lane >> 4) * 8;
    int mrow = wv * 16 + nlo;

    short8 a1[5];
    #pragma unroll
    for (int kt = 0; kt < 5; ++kt)
      a1[kt] = *(const short8*)&A_lds[mrow * ASTR + kt * 32 + koff];
    #pragma unroll
    for (int nt = 0; nt < 8; ++nt) {
      float4v acc = {0.f, 0.f, 0.f, 0.f};
      #pragma unroll
      for (int kt = 0; kt < 5; ++kt) {
        short8 b = *(const short8*)&w1T[(nt * 16 + nlo) * K1PAD + kt * 32 + koff];
        acc = __builtin_amdgcn_mfma_f32_16x16x32_bf16(a1[kt], b, acc, 0, 0, 0);
      }
      float bv = b1[nt * 16 + nlo];
      #pragma unroll
      for (int rg = 0; rg < 4; ++rg) {
        int m = wv * 16 + (lane >> 4) * 4 + rg;
        float hv = fmaxf(acc[rg] + bv, 0.0f);
        h1_lds[m * HSTR + nt * 16 + nlo] = f2bf(hv);
      }
    }
    __syncthreads();

    short8 a2[4];
    #pragma unroll
    for (int kt = 0; kt < 4; ++kt)
      a2[kt] = *(const short8*)&h1_lds[mrow * HSTR + kt * 32 + koff];
    unsigned short* h2 = A_lds;
    #pragma unroll
    for (int nt = 0; nt < 8; ++nt) {
      float4v acc = {0.f, 0.f, 0.f, 0.f};
      #pragma unroll
      for (int kt = 0; kt < 4; ++kt) {
        short8 b = *(const short8*)&w2T[(nt * 16 + nlo) * FEATC + kt * 32 + koff];
        acc = __builtin_amdgcn_mfma_f32_16x16x32_bf16(a2[kt], b, acc, 0, 0, 0);
      }
      float bv = b2[nt * 16 + nlo];
      #pragma unroll
      for (int rg = 0; rg < 4; ++rg) {
        int m = wv * 16 + (lane >> 4) * 4 + rg;
        float hv = fmaxf(acc[rg] + bv, 0.0f);
        h2[m * H2STR + nt * 16 + nlo] = f2bf(hv);
      }
    }
    __syncthreads();

    // ---- layer 3 (128 -> 3) + sigmoid; dense per-point store (no atomics) ----
    if (wv < 3) {
      int j = wv, pp = lane;
      const unsigned short* h2row = h2 + pp * H2STR;
      float sum = b3[j];
      #pragma unroll
      for (int k = 0; k < FEATC; k += 4) {
        ushort4 hv = *(const ushort4*)&h2row[k];
        sum += bf2f(hv.x) * w3[(k+0)*3 + j] + bf2f(hv.y) * w3[(k+1)*3 + j]
             + bf2f(hv.z) * w3[(k+2)*3 + j] + bf2f(hv.w) * w3[(k+3)*3 + j];
      }
      float val = (1.0f / (1.0f + __expf(-sum))) * wlds[pp];
      rgb_pts[(size_t)(base64 + pp) * 4 + j] = val;
    }
  }
}

// ---------------- finish: wave per ray, reduce its list segment
__global__ __launch_bounds__(256)
void finish_kernel(const float* __restrict__ rgb_pts, const int* __restrict__ ray_base,
                   const int* __restrict__ ray_count, const float* __restrict__ acc_ws,
                   float* __restrict__ out) {
  int t = threadIdx.x, lane = t & 63, wv = t >> 6;
  int r = blockIdx.x * 4 + wv;
  int base = ray_base[r], cnt = ray_count[r];
  float s0 = 0.f, s1 = 0.f, s2 = 0.f;
  for (int i = lane; i < cnt; i += 64) {
    const float4 v = *(const float4*)&rgb_pts[(size_t)(base + i) * 4];
    s0 += v.x; s1 += v.y; s2 += v.z;
  }
  #pragma unroll
  for (int d = 32; d; d >>= 1) {
    s0 += __shfl_xor(s0, d); s1 += __shfl_xor(s1, d); s2 += __shfl_xor(s2, d);
  }
  if (lane == 0) {
    float a = 1.0f - acc_ws[r];
    out[r*3+0] = fminf(fmaxf(s0 + a, 0.0f), 1.0f);
    out[r*3+1] = fminf(fmaxf(s1 + a, 0.0f), 1.0f);
    out[r*3+2] = fminf(fmaxf(s2 + a, 0.0f), 1.0f);
  }
}

extern "C" void kernel_launch(void* const* d_in, const int* in_sizes, int n_in,
                              void* d_out, int out_size, void* d_ws, size_t ws_size,
                              hipStream_t stream) {
  const float* rays_o = (const float*)d_in[0];
  const float* rays_d = (const float*)d_in[1];
  const float* dvol   = (const float*)d_in[2];
  const float* avol   = (const float*)d_in[3];
  const float* w1     = (const float*)d_in[4];
  const float* b1     = (const float*)d_in[5];
  const float* w2     = (const float*)d_in[6];
  const float* b2     = (const float*)d_in[7];
  const float* w3     = (const float*)d_in[8];
  const float* b3     = (const float*)d_in[9];
  float* out = (float*)d_out;

  float* weights_ws = (float*)d_ws;                         // NPTS
  float* acc_ws     = weights_ws + NPTS;                    // 2048
  float* rgb_pts    = acc_ws + N_RAYS;                      // (NPTS+64)*4
  int*   count      = (int*)(rgb_pts + (size_t)(NPTS + 64) * 4);
  int*   work_ctr   = count + 1;
  int*   bounds     = work_ctr + 1;                         // 6
  int*   ray_count  = bounds + 6;                           // 2048
  int*   ray_base   = ray_count + N_RAYS;                   // 2048
  int*   block_bounds = ray_base + N_RAYS;                  // 2048*6
  int*   sample_list  = block_bounds + N_RAYS * 6;          // NPTS+64
  unsigned long long* ray_mask = (unsigned long long*)(sample_list + NPTS + 64); // 2048*4
  unsigned short* w1T = (unsigned short*)(ray_mask + N_RAYS * 4);
  unsigned short* w2T = w1T + 128 * K1PAD;
  float* dvolT = (float*)(w2T + 128 * 128);                 // G3 f32
  unsigned short* appT = (unsigned short*)(dvolT + G3);     // G3*28 bf16

  size_t fixed_bytes = ((size_t)NPTS + N_RAYS + (size_t)(NPTS + 64) * 4
                        + 8 + 2 * N_RAYS + N_RAYS * 6 + NPTS + 64) * 4
                     + (size_t)N_RAYS * 4 * 8
                     + (size_t)(128 * K1PAD + 128 * 128) * 2;
  bool usedt = ws_size >= fixed_bytes + (size_t)G3 * 4;
  bool uset  = ws_size >= fixed_bytes + (size_t)G3 * 4 + (size_t)G3 * CHP * 2;

  prep_weights<<<(128 * K1PAD + 128 * 128 + 255) / 256, 256, 0, stream>>>(w1, w2, w1T, w2T);
  if (usedt) {
    dvol_transpose<<<2048, 256, 0, stream>>>(dvol, dvolT);
    ray_kernel<true><<<N_RAYS, 256, 0, stream>>>(rays_o, rays_d, dvolT, weights_ws, acc_ws,
                                                 ray_mask, ray_count, block_bounds);
  } else {
    ray_kernel<false><<<N_RAYS, 256, 0, stream>>>(rays_o, rays_d, dvol, weights_ws, acc_ws,
                                                  ray_mask, ray_count, block_bounds);
  }
  scan_kernel<<<1, 256, 0, stream>>>(ray_count, block_bounds, ray_base, count, work_ctr, bounds);
  scatter_kernel<<<N_RAYS / 4, 256, 0, stream>>>(ray_mask, ray_base, sample_list);
  if (uset) {
    transpose_kernel<<<G3 / 512, 256, 0, stream>>>(avol, appT, bounds);
    shade_kernel<true><<<1024, 256, 0, stream>>>(rays_o, rays_d, avol, appT, w1T, w2T,
                                                 b1, b2, w3, b3, weights_ws, rgb_pts,
                                                 count, work_ctr, sample_list);
  } else {
    shade_kernel<false><<<1024, 256, 0, stream>>>(rays_o, rays_d, avol, appT, w1T, w2T,
                                                  b1, b2, w3, b3, weights_ws, rgb_pts,
                                                  count, work_ctr, sample_list);
  }
  finish_kernel<<<N_RAYS / 4, 256, 0, stream>>>(rgb_pts, ray_base, ray_count, acc_ws, out);
}